// Round 1
// baseline (1498.395 us; speedup 1.0000x reference)
//
#include <hip/hip_runtime.h>

#define NROWS 16384
#define INF   256
#define OUTF  64

typedef __attribute__((ext_vector_type(8))) short  short8;
typedef __attribute__((ext_vector_type(4))) float  floatx4;

__device__ inline unsigned short f2bf(float f) {
    unsigned int u = __float_as_uint(f);
    u += 0x7FFFu + ((u >> 16) & 1u);   // round-to-nearest-even
    return (unsigned short)(u >> 16);
}

__device__ inline short8 cvt8(floatx4 a, floatx4 b) {
    short8 r;
    r[0] = (short)f2bf(a[0]); r[1] = (short)f2bf(a[1]);
    r[2] = (short)f2bf(a[2]); r[3] = (short)f2bf(a[3]);
    r[4] = (short)f2bf(b[0]); r[5] = (short)f2bf(b[1]);
    r[6] = (short)f2bf(b[2]); r[7] = (short)f2bf(b[3]);
    return r;
}

// Kernel 1: h_t[c][n] = (x @ W + b)[n][c], stored bf16 (transposed for kernel 2's
// contiguous B-fragment loads). Wave = 16 rows x 64 cols, K=256.
__global__ __launch_bounds__(256) void proj_kernel(
    const float* __restrict__ x, const float* __restrict__ W,
    const float* __restrict__ bias, unsigned short* __restrict__ h_t)
{
    const int lane = threadIdx.x & 63;
    const int wave = threadIdx.x >> 6;
    const int col  = lane & 15;
    const int quad = lane >> 4;
    const int row0 = blockIdx.x * 64 + wave * 16;

    floatx4 acc[4];
    #pragma unroll
    for (int t = 0; t < 4; ++t) acc[t] = (floatx4)0.0f;

    const float* xp = x + (size_t)(row0 + col) * INF + quad * 8;

    #pragma unroll 2
    for (int k0 = 0; k0 < INF; k0 += 32) {
        floatx4 a0 = *(const floatx4*)(xp + k0);
        floatx4 a1 = *(const floatx4*)(xp + k0 + 4);
        short8 af = cvt8(a0, a1);
        #pragma unroll
        for (int t = 0; t < 4; ++t) {
            // B[k=quad*8+j][n=t*16+col], W row-major [256][64], L2-resident
            const float* wp = W + (size_t)(k0 + quad * 8) * OUTF + t * 16 + col;
            short8 bf;
            #pragma unroll
            for (int j = 0; j < 8; ++j) bf[j] = (short)f2bf(wp[(size_t)j * OUTF]);
            acc[t] = __builtin_amdgcn_mfma_f32_16x16x32_bf16(af, bf, acc[t], 0, 0, 0);
        }
    }

    #pragma unroll
    for (int t = 0; t < 4; ++t) {
        const int c = t * 16 + col;
        const float bv = bias[c];
        #pragma unroll
        for (int r = 0; r < 4; ++r) {
            const int n = row0 + quad * 4 + r;             // C/D: row = quad*4 + r
            h_t[(size_t)c * NROWS + n] = f2bf(acc[t][r] + bv);
        }
    }
}

// Kernel 2: out = relu(adj @ h). adj streamed fp32->bf16 in registers (no reuse,
// no LDS); h_t bf16 B-frags loaded as contiguous 16B from L2. Wave = 16 rows x 64 cols.
__global__ __launch_bounds__(256) void agg_kernel(
    const float* __restrict__ adj, const unsigned short* __restrict__ h_t,
    float* __restrict__ out)
{
    const int lane = threadIdx.x & 63;
    const int wave = threadIdx.x >> 6;
    const int col  = lane & 15;
    const int quad = lane >> 4;
    const int row0 = blockIdx.x * 64 + wave * 16;

    floatx4 acc[4];
    #pragma unroll
    for (int t = 0; t < 4; ++t) acc[t] = (floatx4)0.0f;

    const float* ap = adj + (size_t)(row0 + col) * NROWS + quad * 8;
    const unsigned short* hp[4];
    #pragma unroll
    for (int t = 0; t < 4; ++t)
        hp[t] = h_t + (size_t)(t * 16 + col) * NROWS + quad * 8;

    #pragma unroll 4
    for (int k0 = 0; k0 < NROWS; k0 += 32) {
        floatx4 a0 = *(const floatx4*)(ap + k0);
        floatx4 a1 = *(const floatx4*)(ap + k0 + 4);
        short8 af = cvt8(a0, a1);
        #pragma unroll
        for (int t = 0; t < 4; ++t) {
            short8 bf = *(const short8*)(hp[t] + k0);
            acc[t] = __builtin_amdgcn_mfma_f32_16x16x32_bf16(af, bf, acc[t], 0, 0, 0);
        }
    }

    #pragma unroll
    for (int t = 0; t < 4; ++t) {
        #pragma unroll
        for (int r = 0; r < 4; ++r) {
            const int m = row0 + quad * 4 + r;
            float v = acc[t][r];
            out[(size_t)m * OUTF + t * 16 + col] = v > 0.0f ? v : 0.0f;
        }
    }
}

extern "C" void kernel_launch(void* const* d_in, const int* in_sizes, int n_in,
                              void* d_out, int out_size, void* d_ws, size_t ws_size,
                              hipStream_t stream) {
    const float* x   = (const float*)d_in[0];
    const float* adj = (const float*)d_in[1];
    const float* W   = (const float*)d_in[2];
    const float* b   = (const float*)d_in[3];
    float* out = (float*)d_out;
    unsigned short* h_t = (unsigned short*)d_ws;   // 64*16384 bf16 = 2 MiB

    proj_kernel<<<NROWS / 64, 256, 0, stream>>>(x, W, b, h_t);
    agg_kernel<<<NROWS / 64, 256, 0, stream>>>(adj, h_t, out);
}